// Round 12
// baseline (296.231 us; speedup 1.0000x reference)
//
#include <hip/hip_runtime.h>

#define NN 100000
#define NE 1600000
#define NBUCK 196       // ceil(NN/512) buckets of 512 nodes
#define BUCKCAP 11520   // packed-pair slots per bucket (avg 8192, +36 sigma)
#define SCAP 13312      // ssrc slots per bucket
#define ACHUNK 8192     // edges per partition block

typedef _Float16 f16x8 __attribute__((ext_vector_type(8)));
typedef float f32x4 __attribute__((ext_vector_type(4)));

// ---------------- workspace layout (bytes) ----------------
static const size_t OFF_GCUR  = 0;                         // 256 ints
static const size_t OFF_META  = 1024;                      // NN int4
static const size_t OFF_SSRC  = 1601024;                   // NBUCK*SCAP ints
static const size_t OFF_PAIRS = 12037632;                  // NBUCK*BUCKCAP ints
static const size_t OFF_B1    = 21069312;                  // 128x256 f16
static const size_t OFF_B2    = 21134848;
static const size_t OFF_X16   = 21200384;                  // (N+1)*128 f16 (row N = zeros)
static const size_t OFF_H16   = 46800640;                  // (N+1)*128 f16 (row N = zeros)
static const size_t OFF_AGG   = 72400896;                  // N*128 f16
// end 98.0MB

static __device__ inline float h2f(uint bits) {
    return (float)__builtin_bit_cast(_Float16, (ushort)bits);
}
static __device__ inline ushort f2h(float f) {
    return __builtin_bit_cast(ushort, (_Float16)f);
}
static __device__ inline uint pk2h(float a, float b) {
    return (uint)f2h(a) | ((uint)f2h(b) << 16);
}

__global__ void zero_dummy(ushort* __restrict__ a, ushort* __restrict__ b) {
    int t = threadIdx.x;
    a[(size_t)NN * 128 + t] = 0;
    b[(size_t)NN * 128 + t] = 0;
}

__global__ void init_gcur(int* __restrict__ gcur) {
    gcur[threadIdx.x] = threadIdx.x * BUCKCAP;
}

// single-pass radix partition (unchanged, validated r5-r11)
__global__ __launch_bounds__(256) void partition_pairs(const int* __restrict__ src,
                                                       const int* __restrict__ dst,
                                                       int* __restrict__ gcur,
                                                       int* __restrict__ pairs, int ne) {
    __shared__ int2 staged[ACHUNK];
    __shared__ int  dcache[ACHUNK];
    __shared__ int  hist[256], scanb[256], gbase[256];
    const int t = threadIdx.x;
    const int base = blockIdx.x * ACHUNK;
    const int n = min(ACHUNK, ne - base);

    hist[t] = 0;
    __syncthreads();
    for (int i = t; i < n; i += 256) {
        int d = dst[base + i];
        dcache[i] = d;
        atomicAdd(&hist[d >> 9], 1);
    }
    __syncthreads();

    int v = hist[t];
    scanb[t] = v;
    __syncthreads();
    for (int off = 1; off < 256; off <<= 1) {
        int x = (t >= off) ? scanb[t - off] : 0;
        __syncthreads();
        scanb[t] += x;
        __syncthreads();
    }
    int excl = scanb[t] - v;
    __syncthreads();
    scanb[t] = excl;
    hist[t] = 0;
    gbase[t] = (v > 0) ? atomicAdd(&gcur[t], v) : 0;
    __syncthreads();

    for (int i = t; i < n; i += 256) {
        int d = dcache[i];
        int b = d >> 9;
        int lp = scanb[b] + atomicAdd(&hist[b], 1);
        int2 pr;
        pr.x = (src[base + i] << 9) | (d & 511);
        pr.y = d;
        staged[lp] = pr;
    }
    __syncthreads();

    for (int i = t; i < n; i += 256) {
        int2 pr = staged[i];
        int b = pr.y >> 9;
        pairs[gbase[b] + (i - scanb[b])] = pr.x;
    }
}

// per-bucket CSR build (unchanged, validated)
__global__ __launch_bounds__(512) void bucket_build(const int* __restrict__ gcur,
                                                    const int* __restrict__ pairs,
                                                    int4* __restrict__ meta,
                                                    int* __restrict__ ssrc) {
    __shared__ int s[512];
    __shared__ int exclA[512];
    __shared__ int cur[512];
    const int b = blockIdx.x;
    const int t = threadIdx.x;
    const int pbeg = b * BUCKCAP;
    const int pend = gcur[b];
    const int sbase = b * SCAP;

    cur[t] = 0;
    __syncthreads();
    for (int i = pbeg + t; i < pend; i += 512)
        atomicAdd(&cur[pairs[i] & 511], 1);
    __syncthreads();

    const int deg = cur[t];
    const int pc = (deg + 7) & ~7;
    s[t] = pc;
    __syncthreads();
    for (int off = 1; off < 512; off <<= 1) {
        int x = (t >= off) ? s[t - off] : 0;
        __syncthreads();
        s[t] += x;
        __syncthreads();
    }
    const int excl = s[t] - pc;
    exclA[t] = excl;
    const int node = (b << 9) + t;
    if (node < NN) {
        int4 m;
        m.x = sbase + excl;
        m.y = pc;
        m.z = __builtin_bit_cast(int, 1.0f / (float)(deg > 1 ? deg : 1));
        m.w = 0;
        meta[node] = m;
    }
    __syncthreads();
    const int total = s[511];
    for (int i = t; i < total; i += 512)
        ssrc[sbase + i] = NN;
    cur[t] = 0;
    __syncthreads();
    for (int i = pbeg + t; i < pend; i += 512) {
        int p = pairs[i];
        int loc = p & 511;
        int pos = atomicAdd(&cur[loc], 1);
        ssrc[sbase + exclA[loc] + pos] = p >> 9;
    }
}

// fp32 [n][128] -> f16 [n][128]
__global__ void to_f16(const float* __restrict__ in, ushort* __restrict__ out, int n4) {
    int i = blockIdx.x * blockDim.x + threadIdx.x;
    if (i < n4) {
        float4 v = ((const float4*)in)[i];
        uint2 o;
        o.x = pk2h(v.x, v.y);
        o.y = pk2h(v.z, v.w);
        ((uint2*)out)[i] = o;
    }
}

// pack [Wl;Wr] into Bt f16 [n][k'=256]
__global__ void prep_w(const float* __restrict__ Wl, const float* __restrict__ Wr,
                       ushort* __restrict__ Bt) {
    int id = blockIdx.x * blockDim.x + threadIdx.x;
    if (id >= 32768) return;
    int nw = id & 127;
    int km = id >> 7;
    const float* W = (km < 128) ? Wl : Wr;
    int k = km & 127;
    Bt[(size_t)nw * 256 + km] = f2h(W[k * 128 + nw]);
}

// issue 8 independent feature-row gathers into named regs
#define ISSUE(p, C0, C1)                                                  \
    p##0 = *(const uint*)(feat + (size_t)(C0).x * 128 + loff);            \
    p##1 = *(const uint*)(feat + (size_t)(C0).y * 128 + loff);            \
    p##2 = *(const uint*)(feat + (size_t)(C0).z * 128 + loff);            \
    p##3 = *(const uint*)(feat + (size_t)(C0).w * 128 + loff);            \
    p##4 = *(const uint*)(feat + (size_t)(C1).x * 128 + loff);            \
    p##5 = *(const uint*)(feat + (size_t)(C1).y * 128 + loff);            \
    p##6 = *(const uint*)(feat + (size_t)(C1).z * 128 + loff);            \
    p##7 = *(const uint*)(feat + (size_t)(C1).w * 128 + loff);

#define CONSUME(p)                                                        \
    s0 += h2f(p##0 & 0xffffu); s1 += h2f(p##0 >> 16);                     \
    s2 += h2f(p##1 & 0xffffu); s3 += h2f(p##1 >> 16);                     \
    s0 += h2f(p##2 & 0xffffu); s1 += h2f(p##2 >> 16);                     \
    s2 += h2f(p##3 & 0xffffu); s3 += h2f(p##3 >> 16);                     \
    s4 += h2f(p##4 & 0xffffu); s5 += h2f(p##4 >> 16);                     \
    s6 += h2f(p##5 & 0xffffu); s7 += h2f(p##5 >> 16);                     \
    s4 += h2f(p##6 & 0xffffu); s5 += h2f(p##6 >> 16);                     \
    s6 += h2f(p##7 & 0xffffu); s7 += h2f(p##7 >> 16);

// one wave per node; 2-group software pipeline -> 16 gathers in flight (unchanged)
__global__ __launch_bounds__(256, 6) void aggregate16(const ushort* __restrict__ feat,
                                                      const int4* __restrict__ meta,
                                                      const int* __restrict__ ssrc,
                                                      ushort* __restrict__ outv, int n) {
    int wave = (blockIdx.x * blockDim.x + threadIdx.x) >> 6;
    int lane = threadIdx.x & 63;
    if (wave >= n) return;
    const int4 m = meta[wave];
    int e = m.x;
    const int end = m.x + m.y;
    const float id = __builtin_bit_cast(float, m.z);
    const size_t loff = (size_t)(lane * 2);
    float s0 = 0.f, s1 = 0.f, s2 = 0.f, s3 = 0.f, s4 = 0.f, s5 = 0.f, s6 = 0.f, s7 = 0.f;
    uint a0, a1, a2, a3, a4, a5, a6, a7;
    uint b0, b1, b2, b3, b4, b5, b6, b7;

    if (e < end) {
        int4 c0 = *(const int4*)(ssrc + e);
        int4 c1 = *(const int4*)(ssrc + e + 4);
        ISSUE(a, c0, c1)
        e += 8;
        if (e < end) {
            c0 = *(const int4*)(ssrc + e);
            c1 = *(const int4*)(ssrc + e + 4);
            ISSUE(b, c0, c1)
            e += 8;
            while (e < end) {
                c0 = *(const int4*)(ssrc + e);
                c1 = *(const int4*)(ssrc + e + 4);
                CONSUME(a)
                ISSUE(a, c0, c1)
                e += 8;
                if (e >= end) break;
                c0 = *(const int4*)(ssrc + e);
                c1 = *(const int4*)(ssrc + e + 4);
                CONSUME(b)
                ISSUE(b, c0, c1)
                e += 8;
            }
            CONSUME(a)
            CONSUME(b)
        } else {
            CONSUME(a)
        }
    }
    *(uint*)&outv[(size_t)wave * 128 + loff] =
        pk2h((s0 + s2 + s4 + s6) * id, (s1 + s3 + s5 + s7) * id);
}

// ---- 32-row-tile barrier-free GEMM: grid = NN/32 = 3125 blocks (12/CU issued,
//      8/CU resident -> ~100% occupancy). Wave tile 16x64, acc[4] (~40 VGPR).
//      1-deep register prefetch: kc+1 fragment loads issue before kc's MFMAs.
//      NN % 32 == 0 -> no tail checks.
#define GEMM_DIRECT32(AOP, XOP)                                                        \
    const int t = threadIdx.x;                                                         \
    const int l = t & 63;                                                              \
    const int w = t >> 6;                                                              \
    const int rowBase = blockIdx.x * 32;                                               \
    const int wr = (w & 1) * 16, wc = (w >> 1) * 64;                                   \
    const int grow = rowBase + wr + (l & 15);                                          \
    const int koff = (l >> 4) * 8;                                                     \
    f32x4 acc[4];                                                                      \
    _Pragma("unroll")                                                                  \
    for (int j = 0; j < 4; ++j) acc[j] = 0.0f;                                         \
    const ushort* browBase = Bt + (size_t)(wc + (l & 15)) * 256 + koff;                \
    f16x8 afc, bfc0, bfc1, bfc2, bfc3;                                                 \
    afc  = *(const f16x8*)((AOP) + (size_t)grow * 128 + koff);                         \
    bfc0 = *(const f16x8*)(browBase);                                                  \
    bfc1 = *(const f16x8*)(browBase + 16 * 256);                                       \
    bfc2 = *(const f16x8*)(browBase + 32 * 256);                                       \
    bfc3 = *(const f16x8*)(browBase + 48 * 256);                                       \
    _Pragma("unroll")                                                                  \
    for (int kc = 0; kc < 8; ++kc) {                                                   \
        f16x8 af = afc, bf0 = bfc0, bf1 = bfc1, bf2 = bfc2, bf3 = bfc3;                \
        if (kc < 7) {                                                                  \
            const int kn = kc + 1;                                                     \
            const ushort* srcA = (kn < 4) ? (AOP) : (XOP);                             \
            afc  = *(const f16x8*)(srcA + (size_t)grow * 128 + (kn & 3) * 32 + koff);  \
            bfc0 = *(const f16x8*)(browBase + kn * 32);                                \
            bfc1 = *(const f16x8*)(browBase + 16 * 256 + kn * 32);                     \
            bfc2 = *(const f16x8*)(browBase + 32 * 256 + kn * 32);                     \
            bfc3 = *(const f16x8*)(browBase + 48 * 256 + kn * 32);                     \
        }                                                                              \
        acc[0] = __builtin_amdgcn_mfma_f32_16x16x32_f16(af, bf0, acc[0], 0, 0, 0);     \
        acc[1] = __builtin_amdgcn_mfma_f32_16x16x32_f16(af, bf1, acc[1], 0, 0, 0);     \
        acc[2] = __builtin_amdgcn_mfma_f32_16x16x32_f16(af, bf2, acc[2], 0, 0, 0);     \
        acc[3] = __builtin_amdgcn_mfma_f32_16x16x32_f16(af, bf3, acc[3], 0, 0, 0);     \
    }

// layer 1: h16 = relu(agg@W1l + x@W1r + b1), 8KB LDS stage + coalesced store
__global__ __launch_bounds__(256, 8) void gemm1(const ushort* __restrict__ Aop,
                                                const ushort* __restrict__ Xop,
                                                const ushort* __restrict__ Bt,
                                                const float* __restrict__ bias,
                                                ushort* __restrict__ outH, int n) {
    __shared__ __align__(16) char smem[8192];
    GEMM_DIRECT32(Aop, Xop)

    ushort* sOut = (ushort*)smem;   // 32 x 128 f16 = 8KB
#pragma unroll
    for (int j = 0; j < 4; ++j) {
        int col = wc + j * 16 + (l & 15);
        float bb = bias[col];
#pragma unroll
        for (int q = 0; q < 4; ++q) {
            int row = wr + (l >> 4) * 4 + q;
            sOut[row * 128 + col] = f2h(fmaxf(acc[j][q] + bb, 0.f));
        }
    }
    __syncthreads();
#pragma unroll
    for (int k = 0; k < 2; ++k) {
        int row = k * 16 + (t >> 4);
        int4 v = *(const int4*)(smem + k * 4096 + t * 16);
        *(int4*)(outH + (size_t)(rowBase + row) * 128 + (t & 15) * 8) = v;
    }
}

// layer 2 + fused final linear: out = relu(agg@W2l + h@W2r + b2) @ Wlin + blin
__global__ __launch_bounds__(256, 8) void gemm2(const ushort* __restrict__ Aop,
                                                const ushort* __restrict__ Xop,
                                                const ushort* __restrict__ Bt,
                                                const float* __restrict__ bias,
                                                const float* __restrict__ Wlin,
                                                const float* __restrict__ blin,
                                                float* __restrict__ out, int n) {
    __shared__ __align__(16) char smem[8192];
    GEMM_DIRECT32(Aop, Xop)

    float bb[4], wl0[4], wl1[4];
#pragma unroll
    for (int j = 0; j < 4; ++j) {
        int col = wc + j * 16 + (l & 15);
        bb[j]  = bias[col];
        float2 wv = *(const float2*)&Wlin[col * 2];
        wl0[j] = wv.x;
        wl1[j] = wv.y;
    }
    float* sP = (float*)smem;   // [32 rows][32 slots][2] = 8KB
    const int p = (w >> 1) * 16 + (l & 15);
#pragma unroll
    for (int q = 0; q < 4; ++q) {
        int row = wr + (l >> 4) * 4 + q;
        float p0 = 0.f, p1 = 0.f;
#pragma unroll
        for (int j = 0; j < 4; ++j) {
            float v = fmaxf(acc[j][q] + bb[j], 0.f);
            p0 += v * wl0[j];
            p1 += v * wl1[j];
        }
        int sidx = (p + row) & 31;   // row-keyed slot swizzle
        sP[row * 64 + sidx * 2 + 0] = p0;
        sP[row * 64 + sidx * 2 + 1] = p1;
    }
    __syncthreads();

    if (t < 64) {
        const int row = t >> 1, comp = t & 1;
        float s = 0.f;
#pragma unroll
        for (int k = 0; k < 32; ++k)
            s += sP[row * 64 + (((k + row) & 31)) * 2 + comp];
        out[(size_t)(rowBase + row) * 2 + comp] = s + blin[comp];
    }
}

extern "C" void kernel_launch(void* const* d_in, const int* in_sizes, int n_in,
                              void* d_out, int out_size, void* d_ws, size_t ws_size,
                              hipStream_t stream) {
    const float* x    = (const float*)d_in[0];
    const int*   ei   = (const int*)d_in[1];
    const float* W1l  = (const float*)d_in[2];
    const float* b1   = (const float*)d_in[3];
    const float* W1r  = (const float*)d_in[4];
    const float* W2l  = (const float*)d_in[5];
    const float* b2   = (const float*)d_in[6];
    const float* W2r  = (const float*)d_in[7];
    const float* Wlin = (const float*)d_in[8];
    const float* blin = (const float*)d_in[9];
    float* out = (float*)d_out;

    char* ws = (char*)d_ws;
    int*    gcur    = (int*)(ws + OFF_GCUR);
    int4*   meta    = (int4*)(ws + OFF_META);
    int*    ssrc    = (int*)(ws + OFF_SSRC);
    int*    pairs   = (int*)(ws + OFF_PAIRS);
    ushort* B1c     = (ushort*)(ws + OFF_B1);
    ushort* B2c     = (ushort*)(ws + OFF_B2);
    ushort* x16     = (ushort*)(ws + OFF_X16);
    ushort* h16     = (ushort*)(ws + OFF_H16);
    ushort* agg16   = (ushort*)(ws + OFF_AGG);

    const int* src = ei;
    const int* dst = ei + NE;

    // weight packing + f16 conversion + dummy zero rows
    prep_w<<<128, 256, 0, stream>>>(W1l, W1r, B1c);
    prep_w<<<128, 256, 0, stream>>>(W2l, W2r, B2c);
    to_f16<<<(NN * 32 + 255) / 256, 256, 0, stream>>>(x, x16, NN * 32);
    zero_dummy<<<1, 128, 0, stream>>>(x16, h16);

    // CSR build
    init_gcur<<<1, 256, 0, stream>>>(gcur);
    partition_pairs<<<(NE + ACHUNK - 1) / ACHUNK, 256, 0, stream>>>(src, dst, gcur, pairs, NE);
    bucket_build<<<NBUCK, 512, 0, stream>>>(gcur, pairs, meta, ssrc);

    // layer 1
    aggregate16<<<(NN * 64 + 255) / 256, 256, 0, stream>>>(x16, meta, ssrc, agg16, NN);
    gemm1<<<NN / 32, 256, 0, stream>>>(agg16, x16, B1c, b1, h16, NN);

    // layer 2 + fused final linear
    aggregate16<<<(NN * 64 + 255) / 256, 256, 0, stream>>>(h16, meta, ssrc, agg16, NN);
    gemm2<<<NN / 32, 256, 0, stream>>>(agg16, h16, B2c, b2, Wlin, blin, out, NN);
}

// Round 13
// 210.572 us; speedup vs baseline: 1.4068x; 1.4068x over previous
//
#include <hip/hip_runtime.h>

#define NN 100000
#define NE 1600000
#define NBUCK 196       // ceil(NN/512) buckets of 512 nodes
#define BUCKCAP 11520   // packed-pair slots per bucket (avg 8192, +36 sigma)
#define SCAP 13312      // ssrc slots per bucket
#define ACHUNK 8192     // edges per partition block

typedef _Float16 f16x8 __attribute__((ext_vector_type(8)));
typedef float f32x4 __attribute__((ext_vector_type(4)));

// ---------------- workspace layout (bytes) ----------------
static const size_t OFF_GCUR  = 0;                         // 256 ints
static const size_t OFF_META  = 1024;                      // NN int4
static const size_t OFF_SSRC  = 1601024;                   // NBUCK*SCAP ints
static const size_t OFF_PAIRS = 12037632;                  // NBUCK*BUCKCAP ints
static const size_t OFF_B1    = 21069312;                  // 128x256 f16, fragment-ordered
static const size_t OFF_B2    = 21134848;
static const size_t OFF_X16   = 21200384;                  // (N+1)*128 f16 (row N = zeros)
static const size_t OFF_H16   = 46800640;                  // (N+1)*128 f16 (row N = zeros)
static const size_t OFF_AGG   = 72400896;                  // N*128 f16
// end 98.0MB

static __device__ inline float h2f(uint bits) {
    return (float)__builtin_bit_cast(_Float16, (ushort)bits);
}
static __device__ inline ushort f2h(float f) {
    return __builtin_bit_cast(ushort, (_Float16)f);
}
static __device__ inline uint pk2h(float a, float b) {
    return (uint)f2h(a) | ((uint)f2h(b) << 16);
}

__global__ void zero_dummy(ushort* __restrict__ a, ushort* __restrict__ b) {
    int t = threadIdx.x;
    a[(size_t)NN * 128 + t] = 0;
    b[(size_t)NN * 128 + t] = 0;
}

__global__ void init_gcur(int* __restrict__ gcur) {
    gcur[threadIdx.x] = threadIdx.x * BUCKCAP;
}

// single-pass radix partition (unchanged, validated r5-r12)
__global__ __launch_bounds__(256) void partition_pairs(const int* __restrict__ src,
                                                       const int* __restrict__ dst,
                                                       int* __restrict__ gcur,
                                                       int* __restrict__ pairs, int ne) {
    __shared__ int2 staged[ACHUNK];
    __shared__ int  dcache[ACHUNK];
    __shared__ int  hist[256], scanb[256], gbase[256];
    const int t = threadIdx.x;
    const int base = blockIdx.x * ACHUNK;
    const int n = min(ACHUNK, ne - base);

    hist[t] = 0;
    __syncthreads();
    for (int i = t; i < n; i += 256) {
        int d = dst[base + i];
        dcache[i] = d;
        atomicAdd(&hist[d >> 9], 1);
    }
    __syncthreads();

    int v = hist[t];
    scanb[t] = v;
    __syncthreads();
    for (int off = 1; off < 256; off <<= 1) {
        int x = (t >= off) ? scanb[t - off] : 0;
        __syncthreads();
        scanb[t] += x;
        __syncthreads();
    }
    int excl = scanb[t] - v;
    __syncthreads();
    scanb[t] = excl;
    hist[t] = 0;
    gbase[t] = (v > 0) ? atomicAdd(&gcur[t], v) : 0;
    __syncthreads();

    for (int i = t; i < n; i += 256) {
        int d = dcache[i];
        int b = d >> 9;
        int lp = scanb[b] + atomicAdd(&hist[b], 1);
        int2 pr;
        pr.x = (src[base + i] << 9) | (d & 511);
        pr.y = d;
        staged[lp] = pr;
    }
    __syncthreads();

    for (int i = t; i < n; i += 256) {
        int2 pr = staged[i];
        int b = pr.y >> 9;
        pairs[gbase[b] + (i - scanb[b])] = pr.x;
    }
}

// per-bucket CSR build (unchanged, validated)
__global__ __launch_bounds__(512) void bucket_build(const int* __restrict__ gcur,
                                                    const int* __restrict__ pairs,
                                                    int4* __restrict__ meta,
                                                    int* __restrict__ ssrc) {
    __shared__ int s[512];
    __shared__ int exclA[512];
    __shared__ int cur[512];
    const int b = blockIdx.x;
    const int t = threadIdx.x;
    const int pbeg = b * BUCKCAP;
    const int pend = gcur[b];
    const int sbase = b * SCAP;

    cur[t] = 0;
    __syncthreads();
    for (int i = pbeg + t; i < pend; i += 512)
        atomicAdd(&cur[pairs[i] & 511], 1);
    __syncthreads();

    const int deg = cur[t];
    const int pc = (deg + 7) & ~7;
    s[t] = pc;
    __syncthreads();
    for (int off = 1; off < 512; off <<= 1) {
        int x = (t >= off) ? s[t - off] : 0;
        __syncthreads();
        s[t] += x;
        __syncthreads();
    }
    const int excl = s[t] - pc;
    exclA[t] = excl;
    const int node = (b << 9) + t;
    if (node < NN) {
        int4 m;
        m.x = sbase + excl;
        m.y = pc;
        m.z = __builtin_bit_cast(int, 1.0f / (float)(deg > 1 ? deg : 1));
        m.w = 0;
        meta[node] = m;
    }
    __syncthreads();
    const int total = s[511];
    for (int i = t; i < total; i += 512)
        ssrc[sbase + i] = NN;
    cur[t] = 0;
    __syncthreads();
    for (int i = pbeg + t; i < pend; i += 512) {
        int p = pairs[i];
        int loc = p & 511;
        int pos = atomicAdd(&cur[loc], 1);
        ssrc[sbase + exclA[loc] + pos] = p >> 9;
    }
}

// fp32 [n][128] -> f16 [n][128]
__global__ void to_f16(const float* __restrict__ in, ushort* __restrict__ out, int n4) {
    int i = blockIdx.x * blockDim.x + threadIdx.x;
    if (i < n4) {
        float4 v = ((const float4*)in)[i];
        uint2 o;
        o.x = pk2h(v.x, v.y);
        o.y = pk2h(v.z, v.w);
        ((uint2*)out)[i] = o;
    }
}

// pack [Wl;Wr] into MFMA-fragment-ordered BtP:
// 16B unit u = (k>>7)*2048 + (((k>>5)&3)*4 + ((k>>3)&3))*128 + col, elem = k&7
// so a straight 32KB memcpy into LDS yields conflict-free fragment reads.
__global__ void prep_w(const float* __restrict__ Wl, const float* __restrict__ Wr,
                       ushort* __restrict__ BtP) {
    int id = blockIdx.x * blockDim.x + threadIdx.x;
    if (id >= 32768) return;
    int col = id & 127;
    int k = id >> 7;
    float v = (k < 128) ? Wl[k * 128 + col] : Wr[(k - 128) * 128 + col];
    int u = ((k >> 7) << 11) | (((((k >> 5) & 3) << 2) | ((k >> 3) & 3)) << 7) | col;
    BtP[u * 8 + (k & 7)] = f2h(v);
}

// issue 8 independent feature-row gathers into named regs
#define ISSUE(p, C0, C1)                                                  \
    p##0 = *(const uint*)(feat + (size_t)(C0).x * 128 + loff);            \
    p##1 = *(const uint*)(feat + (size_t)(C0).y * 128 + loff);            \
    p##2 = *(const uint*)(feat + (size_t)(C0).z * 128 + loff);            \
    p##3 = *(const uint*)(feat + (size_t)(C0).w * 128 + loff);            \
    p##4 = *(const uint*)(feat + (size_t)(C1).x * 128 + loff);            \
    p##5 = *(const uint*)(feat + (size_t)(C1).y * 128 + loff);            \
    p##6 = *(const uint*)(feat + (size_t)(C1).z * 128 + loff);            \
    p##7 = *(const uint*)(feat + (size_t)(C1).w * 128 + loff);

#define CONSUME(p)                                                        \
    s0 += h2f(p##0 & 0xffffu); s1 += h2f(p##0 >> 16);                     \
    s2 += h2f(p##1 & 0xffffu); s3 += h2f(p##1 >> 16);                     \
    s0 += h2f(p##2 & 0xffffu); s1 += h2f(p##2 >> 16);                     \
    s2 += h2f(p##3 & 0xffffu); s3 += h2f(p##3 >> 16);                     \
    s4 += h2f(p##4 & 0xffffu); s5 += h2f(p##4 >> 16);                     \
    s6 += h2f(p##5 & 0xffffu); s7 += h2f(p##5 >> 16);                     \
    s4 += h2f(p##6 & 0xffffu); s5 += h2f(p##6 >> 16);                     \
    s6 += h2f(p##7 & 0xffffu); s7 += h2f(p##7 >> 16);

// one wave per node; 2-group software pipeline (unchanged, service-bound)
__global__ __launch_bounds__(256, 6) void aggregate16(const ushort* __restrict__ feat,
                                                      const int4* __restrict__ meta,
                                                      const int* __restrict__ ssrc,
                                                      ushort* __restrict__ outv, int n) {
    int wave = (blockIdx.x * blockDim.x + threadIdx.x) >> 6;
    int lane = threadIdx.x & 63;
    if (wave >= n) return;
    const int4 m = meta[wave];
    int e = m.x;
    const int end = m.x + m.y;
    const float id = __builtin_bit_cast(float, m.z);
    const size_t loff = (size_t)(lane * 2);
    float s0 = 0.f, s1 = 0.f, s2 = 0.f, s3 = 0.f, s4 = 0.f, s5 = 0.f, s6 = 0.f, s7 = 0.f;
    uint a0, a1, a2, a3, a4, a5, a6, a7;
    uint b0, b1, b2, b3, b4, b5, b6, b7;

    if (e < end) {
        int4 c0 = *(const int4*)(ssrc + e);
        int4 c1 = *(const int4*)(ssrc + e + 4);
        ISSUE(a, c0, c1)
        e += 8;
        if (e < end) {
            c0 = *(const int4*)(ssrc + e);
            c1 = *(const int4*)(ssrc + e + 4);
            ISSUE(b, c0, c1)
            e += 8;
            while (e < end) {
                c0 = *(const int4*)(ssrc + e);
                c1 = *(const int4*)(ssrc + e + 4);
                CONSUME(a)
                ISSUE(a, c0, c1)
                e += 8;
                if (e >= end) break;
                c0 = *(const int4*)(ssrc + e);
                c1 = *(const int4*)(ssrc + e + 4);
                CONSUME(b)
                ISSUE(b, c0, c1)
                e += 8;
            }
            CONSUME(a)
            CONSUME(b)
        } else {
            CONSUME(a)
        }
    }
    *(uint*)&outv[(size_t)wave * 128 + loff] =
        pk2h((s0 + s2 + s4 + s6) * id, (s1 + s3 + s5 + s7) * id);
}

// ---- GEMM: 128-row tile, 4 waves, wave = 32 rows x 128 cols, acc[2][8].
//      B staged half-at-a-time (32KB) into LDS via coalesced memcpy of the
//      fragment-ordered BtP; fragment reads are 256B-contiguous per 16-lane
//      phase (conflict-free). A fragments direct-global (row-contiguous,
//      read once). 4 blocks/CU -> all 782 blocks co-resident, no tail.
#define GEMM_LDSB(AOP, XOP)                                                            \
    const int t = threadIdx.x;                                                         \
    const int l = t & 63;                                                              \
    const int w = t >> 6;                                                              \
    const int c = l & 15, g = l >> 4;                                                  \
    const int rowBase = blockIdx.x * 128;                                              \
    const int wr = w * 32;                                                             \
    f32x4 acc[2][8];                                                                   \
    _Pragma("unroll")                                                                  \
    for (int i = 0; i < 2; ++i)                                                        \
        _Pragma("unroll")                                                              \
        for (int j = 0; j < 8; ++j) acc[i][j] = 0.0f;                                  \
    int grow_[2];                                                                      \
    _Pragma("unroll")                                                                  \
    for (int i = 0; i < 2; ++i) {                                                      \
        int r = rowBase + wr + i * 16 + c;                                             \
        grow_[i] = (r < n) ? r : (n - 1);                                              \
    }                                                                                  \
    for (int s = 0; s < 2; ++s) {                                                      \
        __syncthreads();                                                               \
        {                                                                              \
            const int4* gB = (const int4*)BtP + s * 2048;                              \
            int4* sB = (int4*)smem;                                                    \
            _Pragma("unroll 4")                                                        \
            for (int i = 0; i < 8; ++i)                                                \
                sB[i * 256 + t] = gB[i * 256 + t];                                     \
        }                                                                              \
        __syncthreads();                                                               \
        const ushort* srcA = s ? (XOP) : (AOP);                                        \
        f16x8 afc0 = *(const f16x8*)(srcA + (size_t)grow_[0] * 128 + g * 8);           \
        f16x8 afc1 = *(const f16x8*)(srcA + (size_t)grow_[1] * 128 + g * 8);           \
        _Pragma("unroll")                                                              \
        for (int kc = 0; kc < 4; ++kc) {                                               \
            f16x8 af0 = afc0, af1 = afc1;                                              \
            if (kc < 3) {                                                              \
                afc0 = *(const f16x8*)(srcA + (size_t)grow_[0] * 128 +                 \
                                       (kc + 1) * 32 + g * 8);                         \
                afc1 = *(const f16x8*)(srcA + (size_t)grow_[1] * 128 +                 \
                                       (kc + 1) * 32 + g * 8);                         \
            }                                                                          \
            _Pragma("unroll")                                                          \
            for (int j = 0; j < 8; ++j) {                                              \
                f16x8 bf = *(const f16x8*)(smem +                                      \
                           (((kc * 4 + g) * 128 + j * 16 + c) << 4));                  \
                acc[0][j] = __builtin_amdgcn_mfma_f32_16x16x32_f16(af0, bf,            \
                                                                   acc[0][j], 0, 0, 0);\
                acc[1][j] = __builtin_amdgcn_mfma_f32_16x16x32_f16(af1, bf,            \
                                                                   acc[1][j], 0, 0, 0);\
            }                                                                          \
        }                                                                              \
    }                                                                                  \
    __syncthreads();

// layer 1: h16 = relu(agg@W1l + x@W1r + b1), LDS-staged coalesced f16 store
__global__ __launch_bounds__(256, 4) void gemm1(const ushort* __restrict__ Aop,
                                                const ushort* __restrict__ Xop,
                                                const ushort* __restrict__ BtP,
                                                const float* __restrict__ bias,
                                                ushort* __restrict__ outH, int n) {
    __shared__ __align__(16) char smem[32768];
    GEMM_LDSB(Aop, Xop)

    ushort* sOut = (ushort*)smem;   // reuse: 128 x 128 f16 = 32KB
#pragma unroll
    for (int j = 0; j < 8; ++j) {
        int col = j * 16 + c;
        float bb = bias[col];
#pragma unroll
        for (int i = 0; i < 2; ++i)
#pragma unroll
            for (int q = 0; q < 4; ++q) {
                int row = wr + i * 16 + g * 4 + q;
                sOut[row * 128 + col] = f2h(fmaxf(acc[i][j][q] + bb, 0.f));
            }
    }
    __syncthreads();
#pragma unroll
    for (int k2 = 0; k2 < 8; ++k2) {
        int row = k2 * 16 + (t >> 4);
        int4 v = *(const int4*)(smem + k2 * 4096 + t * 16);
        if (rowBase + row < n)
            *(int4*)(outH + (size_t)(rowBase + row) * 128 + (t & 15) * 8) = v;
    }
}

// layer 2 + fused final linear: out = relu(agg@W2l + h@W2r + b2) @ Wlin + blin
__global__ __launch_bounds__(256, 4) void gemm2(const ushort* __restrict__ Aop,
                                                const ushort* __restrict__ Xop,
                                                const ushort* __restrict__ BtP,
                                                const float* __restrict__ bias,
                                                const float* __restrict__ Wlin,
                                                const float* __restrict__ blin,
                                                float* __restrict__ out, int n) {
    __shared__ __align__(16) char smem[32768];
    GEMM_LDSB(Aop, Xop)

    float* sP = (float*)smem;   // reuse: [128 rows][16 slots][2] f32 = 16KB
#pragma unroll
    for (int i = 0; i < 2; ++i)
#pragma unroll
        for (int q = 0; q < 4; ++q) {
            int row = wr + i * 16 + g * 4 + q;
            float p0 = 0.f, p1 = 0.f;
#pragma unroll
            for (int j = 0; j < 8; ++j) {
                int col = j * 16 + c;
                float v = fmaxf(acc[i][j][q] + bias[col], 0.f);
                float2 wv = *(const float2*)&Wlin[col * 2];
                p0 += v * wv.x;
                p1 += v * wv.y;
            }
            int sidx = (c + row) & 15;   // row-keyed slot rotation (store side)
            sP[row * 32 + sidx * 2 + 0] = p0;
            sP[row * 32 + sidx * 2 + 1] = p1;
        }
    __syncthreads();

    // 256 threads reduce 256 outputs (128 rows x 2 comps); rotated read
    {
        const int row = t >> 1, comp = t & 1;
        float s = 0.f;
#pragma unroll
        for (int k2 = 0; k2 < 16; ++k2)
            s += sP[row * 32 + (((k2 + row) & 15)) * 2 + comp];
        if (rowBase + row < n)
            out[(size_t)(rowBase + row) * 2 + comp] = s + blin[comp];
    }
}

extern "C" void kernel_launch(void* const* d_in, const int* in_sizes, int n_in,
                              void* d_out, int out_size, void* d_ws, size_t ws_size,
                              hipStream_t stream) {
    const float* x    = (const float*)d_in[0];
    const int*   ei   = (const int*)d_in[1];
    const float* W1l  = (const float*)d_in[2];
    const float* b1   = (const float*)d_in[3];
    const float* W1r  = (const float*)d_in[4];
    const float* W2l  = (const float*)d_in[5];
    const float* b2   = (const float*)d_in[6];
    const float* W2r  = (const float*)d_in[7];
    const float* Wlin = (const float*)d_in[8];
    const float* blin = (const float*)d_in[9];
    float* out = (float*)d_out;

    char* ws = (char*)d_ws;
    int*    gcur    = (int*)(ws + OFF_GCUR);
    int4*   meta    = (int4*)(ws + OFF_META);
    int*    ssrc    = (int*)(ws + OFF_SSRC);
    int*    pairs   = (int*)(ws + OFF_PAIRS);
    ushort* B1c     = (ushort*)(ws + OFF_B1);
    ushort* B2c     = (ushort*)(ws + OFF_B2);
    ushort* x16     = (ushort*)(ws + OFF_X16);
    ushort* h16     = (ushort*)(ws + OFF_H16);
    ushort* agg16   = (ushort*)(ws + OFF_AGG);

    const int* src = ei;
    const int* dst = ei + NE;

    // weight packing (fragment order) + f16 conversion + dummy zero rows
    prep_w<<<128, 256, 0, stream>>>(W1l, W1r, B1c);
    prep_w<<<128, 256, 0, stream>>>(W2l, W2r, B2c);
    to_f16<<<(NN * 32 + 255) / 256, 256, 0, stream>>>(x, x16, NN * 32);
    zero_dummy<<<1, 128, 0, stream>>>(x16, h16);

    // CSR build
    init_gcur<<<1, 256, 0, stream>>>(gcur);
    partition_pairs<<<(NE + ACHUNK - 1) / ACHUNK, 256, 0, stream>>>(src, dst, gcur, pairs, NE);
    bucket_build<<<NBUCK, 512, 0, stream>>>(gcur, pairs, meta, ssrc);

    // layer 1
    aggregate16<<<(NN * 64 + 255) / 256, 256, 0, stream>>>(x16, meta, ssrc, agg16, NN);
    gemm1<<<(NN + 127) / 128, 256, 0, stream>>>(agg16, x16, B1c, b1, h16, NN);

    // layer 2 + fused final linear
    aggregate16<<<(NN * 64 + 255) / 256, 256, 0, stream>>>(h16, meta, ssrc, agg16, NN);
    gemm2<<<(NN + 127) / 128, 256, 0, stream>>>(agg16, h16, B2c, b2, Wlin, blin, out, NN);
}

// Round 14
// 207.442 us; speedup vs baseline: 1.4280x; 1.0151x over previous
//
#include <hip/hip_runtime.h>

#define NN 100000
#define NE 1600000
#define NBUCK 196       // ceil(NN/512) buckets of 512 nodes
#define BUCKCAP 11520   // packed-pair slots per bucket (avg 8192, +36 sigma)
#define SCAP 13312      // ssrc slots per bucket
#define ACHUNK 8192     // edges per partition block

typedef _Float16 f16x8 __attribute__((ext_vector_type(8)));
typedef float f32x4 __attribute__((ext_vector_type(4)));

// ---------------- workspace layout (bytes) ----------------
static const size_t OFF_GCUR  = 0;                         // 256 ints
static const size_t OFF_META  = 1024;                      // NN int4
static const size_t OFF_SSRC  = 1601024;                   // NBUCK*SCAP ints
static const size_t OFF_PAIRS = 12037632;                  // NBUCK*BUCKCAP ints
static const size_t OFF_B1    = 21069312;                  // 128x256 f16, fragment-ordered
static const size_t OFF_B2    = 21134848;
static const size_t OFF_X16   = 21200384;                  // (N+1)*128 f16 (row N = zeros)
static const size_t OFF_H16   = 46800640;                  // (N+1)*128 f16 (row N = zeros)
static const size_t OFF_AGG   = 72400896;                  // N*128 f16
// end 98.0MB

static __device__ inline float h2f(uint bits) {
    return (float)__builtin_bit_cast(_Float16, (ushort)bits);
}
static __device__ inline ushort f2h(float f) {
    return __builtin_bit_cast(ushort, (_Float16)f);
}
static __device__ inline uint pk2h(float a, float b) {
    return (uint)f2h(a) | ((uint)f2h(b) << 16);
}

// fused tiny init: bucket cursors + dummy zero rows (saves 1 launch)
__global__ void misc_init(int* __restrict__ gcur, ushort* __restrict__ a,
                          ushort* __restrict__ b) {
    int t = threadIdx.x;
    gcur[t] = t * BUCKCAP;
    if (t < 128) {
        a[(size_t)NN * 128 + t] = 0;
        b[(size_t)NN * 128 + t] = 0;
    }
}

// single-pass radix partition (unchanged, validated r5-r13)
__global__ __launch_bounds__(256) void partition_pairs(const int* __restrict__ src,
                                                       const int* __restrict__ dst,
                                                       int* __restrict__ gcur,
                                                       int* __restrict__ pairs, int ne) {
    __shared__ int2 staged[ACHUNK];
    __shared__ int  dcache[ACHUNK];
    __shared__ int  hist[256], scanb[256], gbase[256];
    const int t = threadIdx.x;
    const int base = blockIdx.x * ACHUNK;
    const int n = min(ACHUNK, ne - base);

    hist[t] = 0;
    __syncthreads();
    for (int i = t; i < n; i += 256) {
        int d = dst[base + i];
        dcache[i] = d;
        atomicAdd(&hist[d >> 9], 1);
    }
    __syncthreads();

    int v = hist[t];
    scanb[t] = v;
    __syncthreads();
    for (int off = 1; off < 256; off <<= 1) {
        int x = (t >= off) ? scanb[t - off] : 0;
        __syncthreads();
        scanb[t] += x;
        __syncthreads();
    }
    int excl = scanb[t] - v;
    __syncthreads();
    scanb[t] = excl;
    hist[t] = 0;
    gbase[t] = (v > 0) ? atomicAdd(&gcur[t], v) : 0;
    __syncthreads();

    for (int i = t; i < n; i += 256) {
        int d = dcache[i];
        int b = d >> 9;
        int lp = scanb[b] + atomicAdd(&hist[b], 1);
        int2 pr;
        pr.x = (src[base + i] << 9) | (d & 511);
        pr.y = d;
        staged[lp] = pr;
    }
    __syncthreads();

    for (int i = t; i < n; i += 256) {
        int2 pr = staged[i];
        int b = pr.y >> 9;
        pairs[gbase[b] + (i - scanb[b])] = pr.x;
    }
}

// per-bucket CSR build; pad-fill only each node's tail [deg, pc)
__global__ __launch_bounds__(512) void bucket_build(const int* __restrict__ gcur,
                                                    const int* __restrict__ pairs,
                                                    int4* __restrict__ meta,
                                                    int* __restrict__ ssrc) {
    __shared__ int s[512];
    __shared__ int exclA[512];
    __shared__ int cur[512];
    const int b = blockIdx.x;
    const int t = threadIdx.x;
    const int pbeg = b * BUCKCAP;
    const int pend = gcur[b];
    const int sbase = b * SCAP;

    cur[t] = 0;
    __syncthreads();
    for (int i = pbeg + t; i < pend; i += 512)
        atomicAdd(&cur[pairs[i] & 511], 1);
    __syncthreads();

    const int deg = cur[t];
    const int pc = (deg + 7) & ~7;
    s[t] = pc;
    __syncthreads();
    for (int off = 1; off < 512; off <<= 1) {
        int x = (t >= off) ? s[t - off] : 0;
        __syncthreads();
        s[t] += x;
        __syncthreads();
    }
    const int excl = s[t] - pc;
    exclA[t] = excl;
    const int node = (b << 9) + t;
    if (node < NN) {
        int4 m;
        m.x = sbase + excl;
        m.y = pc;
        m.z = __builtin_bit_cast(int, 1.0f / (float)(deg > 1 ? deg : 1));
        m.w = 0;
        meta[node] = m;
    }
    // tail-only pad fill: slots [deg, pc) of this node's segment
    for (int i = deg; i < pc; ++i)
        ssrc[sbase + excl + i] = NN;
    cur[t] = 0;
    __syncthreads();
    for (int i = pbeg + t; i < pend; i += 512) {
        int p = pairs[i];
        int loc = p & 511;
        int pos = atomicAdd(&cur[loc], 1);
        ssrc[sbase + exclA[loc] + pos] = p >> 9;
    }
}

// fp32 [n][128] -> f16 [n][128]
__global__ void to_f16(const float* __restrict__ in, ushort* __restrict__ out, int n4) {
    int i = blockIdx.x * blockDim.x + threadIdx.x;
    if (i < n4) {
        float4 v = ((const float4*)in)[i];
        uint2 o;
        o.x = pk2h(v.x, v.y);
        o.y = pk2h(v.z, v.w);
        ((uint2*)out)[i] = o;
    }
}

// pack BOTH layers' [Wl;Wr] into MFMA-fragment-ordered BtP (saves 1 launch):
// 16B unit u = (k>>7)*2048 + (((k>>5)&3)*4 + ((k>>3)&3))*128 + col, elem = k&7
__global__ void prep_w_all(const float* __restrict__ W1l, const float* __restrict__ W1r,
                           const float* __restrict__ W2l, const float* __restrict__ W2r,
                           ushort* __restrict__ B1, ushort* __restrict__ B2) {
    int id = blockIdx.x * blockDim.x + threadIdx.x;   // 65536 total
    int which = id >> 15;
    int r = id & 32767;
    int col = r & 127;
    int k = r >> 7;
    const float* Wl = which ? W2l : W1l;
    const float* Wr = which ? W2r : W1r;
    ushort* Bt = which ? B2 : B1;
    float v = (k < 128) ? Wl[k * 128 + col] : Wr[(k - 128) * 128 + col];
    int u = ((k >> 7) << 11) | (((((k >> 5) & 3) << 2) | ((k >> 3) & 3)) << 7) | col;
    Bt[u * 8 + (k & 7)] = f2h(v);
}

// issue 8 independent feature-row gathers (scalar row index, per-lane offset)
#define ISSUE(p, C0, C1)                                                  \
    p##0 = *(const uint*)(fb + (size_t)(C0).x * 128);                     \
    p##1 = *(const uint*)(fb + (size_t)(C0).y * 128);                     \
    p##2 = *(const uint*)(fb + (size_t)(C0).z * 128);                     \
    p##3 = *(const uint*)(fb + (size_t)(C0).w * 128);                     \
    p##4 = *(const uint*)(fb + (size_t)(C1).x * 128);                     \
    p##5 = *(const uint*)(fb + (size_t)(C1).y * 128);                     \
    p##6 = *(const uint*)(fb + (size_t)(C1).z * 128);                     \
    p##7 = *(const uint*)(fb + (size_t)(C1).w * 128);

#define CONSUME(p)                                                        \
    s0 += h2f(p##0 & 0xffffu); s1 += h2f(p##0 >> 16);                     \
    s2 += h2f(p##1 & 0xffffu); s3 += h2f(p##1 >> 16);                     \
    s0 += h2f(p##2 & 0xffffu); s1 += h2f(p##2 >> 16);                     \
    s2 += h2f(p##3 & 0xffffu); s3 += h2f(p##3 >> 16);                     \
    s4 += h2f(p##4 & 0xffffu); s5 += h2f(p##4 >> 16);                     \
    s6 += h2f(p##5 & 0xffffu); s7 += h2f(p##5 >> 16);                     \
    s4 += h2f(p##6 & 0xffffu); s5 += h2f(p##6 >> 16);                     \
    s6 += h2f(p##7 & 0xffffu); s7 += h2f(p##7 >> 16);

// one wave per node; 2-group pipeline; meta/index chain scalarized via
// readfirstlane -> s_load index reads + SGPR-base gathers (VALU addr -> SALU)
__global__ __launch_bounds__(256, 6) void aggregate16(const ushort* __restrict__ feat,
                                                      const int4* __restrict__ meta,
                                                      const int* __restrict__ ssrc,
                                                      ushort* __restrict__ outv, int n) {
    int wave = (blockIdx.x * blockDim.x + threadIdx.x) >> 6;
    int lane = threadIdx.x & 63;
    if (wave >= n) return;
    const int4 m = meta[wave];
    int e = __builtin_amdgcn_readfirstlane(m.x);
    const int end = e + __builtin_amdgcn_readfirstlane(m.y);
    const float id = __builtin_bit_cast(float, __builtin_amdgcn_readfirstlane(m.z));
    const ushort* fb = feat + lane * 2;   // per-lane base; row index stays scalar
    float s0 = 0.f, s1 = 0.f, s2 = 0.f, s3 = 0.f, s4 = 0.f, s5 = 0.f, s6 = 0.f, s7 = 0.f;
    uint a0, a1, a2, a3, a4, a5, a6, a7;
    uint b0, b1, b2, b3, b4, b5, b6, b7;

    if (e < end) {
        int4 c0 = *(const int4*)(ssrc + e);
        int4 c1 = *(const int4*)(ssrc + e + 4);
        ISSUE(a, c0, c1)
        e += 8;
        if (e < end) {
            c0 = *(const int4*)(ssrc + e);
            c1 = *(const int4*)(ssrc + e + 4);
            ISSUE(b, c0, c1)
            e += 8;
            while (e < end) {
                c0 = *(const int4*)(ssrc + e);
                c1 = *(const int4*)(ssrc + e + 4);
                CONSUME(a)
                ISSUE(a, c0, c1)
                e += 8;
                if (e >= end) break;
                c0 = *(const int4*)(ssrc + e);
                c1 = *(const int4*)(ssrc + e + 4);
                CONSUME(b)
                ISSUE(b, c0, c1)
                e += 8;
            }
            CONSUME(a)
            CONSUME(b)
        } else {
            CONSUME(a)
        }
    }
    *(uint*)&outv[(size_t)wave * 128 + (size_t)(lane * 2)] =
        pk2h((s0 + s2 + s4 + s6) * id, (s1 + s3 + s5 + s7) * id);
}

// ---- GEMM: 128-row tile, 4 waves, wave = 32 rows x 128 cols, acc[2][8].
//      B staged half-at-a-time (32KB) into LDS via coalesced memcpy of the
//      fragment-ordered BtP; A fragments direct-global. (validated r13)
#define GEMM_LDSB(AOP, XOP)                                                            \
    const int t = threadIdx.x;                                                         \
    const int l = t & 63;                                                              \
    const int w = t >> 6;                                                              \
    const int c = l & 15, g = l >> 4;                                                  \
    const int rowBase = blockIdx.x * 128;                                              \
    const int wr = w * 32;                                                             \
    f32x4 acc[2][8];                                                                   \
    _Pragma("unroll")                                                                  \
    for (int i = 0; i < 2; ++i)                                                        \
        _Pragma("unroll")                                                              \
        for (int j = 0; j < 8; ++j) acc[i][j] = 0.0f;                                  \
    int grow_[2];                                                                      \
    _Pragma("unroll")                                                                  \
    for (int i = 0; i < 2; ++i) {                                                      \
        int r = rowBase + wr + i * 16 + c;                                             \
        grow_[i] = (r < n) ? r : (n - 1);                                              \
    }                                                                                  \
    for (int s = 0; s < 2; ++s) {                                                      \
        __syncthreads();                                                               \
        {                                                                              \
            const int4* gB = (const int4*)BtP + s * 2048;                              \
            int4* sB = (int4*)smem;                                                    \
            _Pragma("unroll 4")                                                        \
            for (int i = 0; i < 8; ++i)                                                \
                sB[i * 256 + t] = gB[i * 256 + t];                                     \
        }                                                                              \
        __syncthreads();                                                               \
        const ushort* srcA = s ? (XOP) : (AOP);                                        \
        f16x8 afc0 = *(const f16x8*)(srcA + (size_t)grow_[0] * 128 + g * 8);           \
        f16x8 afc1 = *(const f16x8*)(srcA + (size_t)grow_[1] * 128 + g * 8);           \
        _Pragma("unroll")                                                              \
        for (int kc = 0; kc < 4; ++kc) {                                               \
            f16x8 af0 = afc0, af1 = afc1;                                              \
            if (kc < 3) {                                                              \
                afc0 = *(const f16x8*)(srcA + (size_t)grow_[0] * 128 +                 \
                                       (kc + 1) * 32 + g * 8);                         \
                afc1 = *(const f16x8*)(srcA + (size_t)grow_[1] * 128 +                 \
                                       (kc + 1) * 32 + g * 8);                         \
            }                                                                          \
            _Pragma("unroll")                                                          \
            for (int j = 0; j < 8; ++j) {                                              \
                f16x8 bf = *(const f16x8*)(smem +                                      \
                           (((kc * 4 + g) * 128 + j * 16 + c) << 4));                  \
                acc[0][j] = __builtin_amdgcn_mfma_f32_16x16x32_f16(af0, bf,            \
                                                                   acc[0][j], 0, 0, 0);\
                acc[1][j] = __builtin_amdgcn_mfma_f32_16x16x32_f16(af1, bf,            \
                                                                   acc[1][j], 0, 0, 0);\
            }                                                                          \
        }                                                                              \
    }                                                                                  \
    __syncthreads();

// layer 1: h16 = relu(agg@W1l + x@W1r + b1), LDS-staged coalesced f16 store
__global__ __launch_bounds__(256, 4) void gemm1(const ushort* __restrict__ Aop,
                                                const ushort* __restrict__ Xop,
                                                const ushort* __restrict__ BtP,
                                                const float* __restrict__ bias,
                                                ushort* __restrict__ outH, int n) {
    __shared__ __align__(16) char smem[32768];
    GEMM_LDSB(Aop, Xop)

    ushort* sOut = (ushort*)smem;   // reuse: 128 x 128 f16 = 32KB
#pragma unroll
    for (int j = 0; j < 8; ++j) {
        int col = j * 16 + c;
        float bb = bias[col];
#pragma unroll
        for (int i = 0; i < 2; ++i)
#pragma unroll
            for (int q = 0; q < 4; ++q) {
                int row = wr + i * 16 + g * 4 + q;
                sOut[row * 128 + col] = f2h(fmaxf(acc[i][j][q] + bb, 0.f));
            }
    }
    __syncthreads();
#pragma unroll
    for (int k2 = 0; k2 < 8; ++k2) {
        int row = k2 * 16 + (t >> 4);
        int4 v = *(const int4*)(smem + k2 * 4096 + t * 16);
        if (rowBase + row < n)
            *(int4*)(outH + (size_t)(rowBase + row) * 128 + (t & 15) * 8) = v;
    }
}

// layer 2 + fused final linear: out = relu(agg@W2l + h@W2r + b2) @ Wlin + blin
__global__ __launch_bounds__(256, 4) void gemm2(const ushort* __restrict__ Aop,
                                                const ushort* __restrict__ Xop,
                                                const ushort* __restrict__ BtP,
                                                const float* __restrict__ bias,
                                                const float* __restrict__ Wlin,
                                                const float* __restrict__ blin,
                                                float* __restrict__ out, int n) {
    __shared__ __align__(16) char smem[32768];
    GEMM_LDSB(Aop, Xop)

    float* sP = (float*)smem;   // reuse: [128 rows][16 slots][2] f32 = 16KB
#pragma unroll
    for (int i = 0; i < 2; ++i)
#pragma unroll
        for (int q = 0; q < 4; ++q) {
            int row = wr + i * 16 + g * 4 + q;
            float p0 = 0.f, p1 = 0.f;
#pragma unroll
            for (int j = 0; j < 8; ++j) {
                int col = j * 16 + c;
                float v = fmaxf(acc[i][j][q] + bias[col], 0.f);
                float2 wv = *(const float2*)&Wlin[col * 2];
                p0 += v * wv.x;
                p1 += v * wv.y;
            }
            int sidx = (c + row) & 15;   // row-keyed slot rotation (store side)
            sP[row * 32 + sidx * 2 + 0] = p0;
            sP[row * 32 + sidx * 2 + 1] = p1;
        }
    __syncthreads();

    {
        const int row = t >> 1, comp = t & 1;
        float s = 0.f;
#pragma unroll
        for (int k2 = 0; k2 < 16; ++k2)
            s += sP[row * 32 + (((k2 + row) & 15)) * 2 + comp];
        if (rowBase + row < n)
            out[(size_t)(rowBase + row) * 2 + comp] = s + blin[comp];
    }
}

extern "C" void kernel_launch(void* const* d_in, const int* in_sizes, int n_in,
                              void* d_out, int out_size, void* d_ws, size_t ws_size,
                              hipStream_t stream) {
    const float* x    = (const float*)d_in[0];
    const int*   ei   = (const int*)d_in[1];
    const float* W1l  = (const float*)d_in[2];
    const float* b1   = (const float*)d_in[3];
    const float* W1r  = (const float*)d_in[4];
    const float* W2l  = (const float*)d_in[5];
    const float* b2   = (const float*)d_in[6];
    const float* W2r  = (const float*)d_in[7];
    const float* Wlin = (const float*)d_in[8];
    const float* blin = (const float*)d_in[9];
    float* out = (float*)d_out;

    char* ws = (char*)d_ws;
    int*    gcur    = (int*)(ws + OFF_GCUR);
    int4*   meta    = (int4*)(ws + OFF_META);
    int*    ssrc    = (int*)(ws + OFF_SSRC);
    int*    pairs   = (int*)(ws + OFF_PAIRS);
    ushort* B1c     = (ushort*)(ws + OFF_B1);
    ushort* B2c     = (ushort*)(ws + OFF_B2);
    ushort* x16     = (ushort*)(ws + OFF_X16);
    ushort* h16     = (ushort*)(ws + OFF_H16);
    ushort* agg16   = (ushort*)(ws + OFF_AGG);

    const int* src = ei;
    const int* dst = ei + NE;

    // init + weight packing + f16 conversion
    misc_init<<<1, 256, 0, stream>>>(gcur, x16, h16);
    prep_w_all<<<256, 256, 0, stream>>>(W1l, W1r, W2l, W2r, B1c, B2c);
    to_f16<<<(NN * 32 + 255) / 256, 256, 0, stream>>>(x, x16, NN * 32);

    // CSR build
    partition_pairs<<<(NE + ACHUNK - 1) / ACHUNK, 256, 0, stream>>>(src, dst, gcur, pairs, NE);
    bucket_build<<<NBUCK, 512, 0, stream>>>(gcur, pairs, meta, ssrc);

    // layer 1
    aggregate16<<<(NN * 64 + 255) / 256, 256, 0, stream>>>(x16, meta, ssrc, agg16, NN);
    gemm1<<<(NN + 127) / 128, 256, 0, stream>>>(agg16, x16, B1c, b1, h16, NN);

    // layer 2 + fused final linear
    aggregate16<<<(NN * 64 + 255) / 256, 256, 0, stream>>>(h16, meta, ssrc, agg16, NN);
    gemm2<<<(NN + 127) / 128, 256, 0, stream>>>(agg16, h16, B2c, b2, Wlin, blin, out, NN);
}